// Round 1
// baseline (574.212 us; speedup 1.0000x reference)
//
#include <hip/hip_runtime.h>
#include <math.h>

#define N_DIM 1000
#define P_DIM 50000
#define Z_DIM 10
#define L_DIM 5
#define NT 256
#define NB 196          // ceil(50000/256)
#define NSPLIT 4
#define NCHUNK 250      // N_DIM / NSPLIT
#define NEG_BIG (-3.0e38f)

// ---- workspace layout (floats) ----
constexpr size_t ZP      = (size_t)Z_DIM * P_DIM;      // 500000
constexpr size_t OFF_ZTR = 0;                          // [Z][P]
constexpr size_t OFF_W   = ZP;                         // [Z][P]
constexpr size_t OFF_WK  = 2 * ZP;                     // [P]
constexpr size_t OFF_RTZ = 2 * ZP + P_DIM;             // [P]
constexpr size_t OFF_LG  = 2 * ZP + 2 * P_DIM;         // [P]
constexpr size_t OFF_ZZ  = 2 * ZP + 3 * P_DIM;         // [Z*Z], reserve 128
constexpr size_t OFF_PM0 = OFF_ZZ + 128;               // partials buf0 max  [NB]
constexpr size_t OFF_PS0 = OFF_PM0 + NB;               // partials buf0 sum  [NB]
constexpr size_t OFF_PM1 = OFF_PS0 + NB;               // partials buf1 max  [NB]
constexpr size_t OFF_PS1 = OFF_PM1 + NB;               // partials buf1 sum  [NB]

// ---- output layout (floats) ----
constexpr size_t OUT_MW = 0;
constexpr size_t OUT_VW = (size_t)L_DIM * Z_DIM * P_DIM;          // 2,500,000
constexpr size_t OUT_AL = OUT_VW + (size_t)L_DIM * Z_DIM;         // 2,500,050

// Online-softmax merge of (m,e) pairs. NEG_BIG (not -INF) avoids NaN from inf-inf.
__device__ inline void online_merge(float& m, float& e, float m2, float e2) {
    float M = fmaxf(m, m2);
    e = e * __expf(m - M) + e2 * __expf(m2 - M);
    m = M;
}

// Block-wide online-softmax reduction; all threads exit with the merged (m,e).
__device__ inline void block_merge(float& m, float& e, float* sm, float* se, float* bro) {
    int lane = threadIdx.x & 63;
    int wid  = threadIdx.x >> 6;
    #pragma unroll
    for (int off = 32; off > 0; off >>= 1) {
        float m2 = __shfl_xor(m, off);
        float e2 = __shfl_xor(e, off);
        online_merge(m, e, m2, e2);
    }
    if (lane == 0) { sm[wid] = m; se[wid] = e; }
    __syncthreads();
    if (threadIdx.x == 0) {
        float M = sm[0], E = se[0];
        #pragma unroll
        for (int w = 1; w < NT / 64; w++) online_merge(M, E, sm[w], se[w]);
        bro[0] = M; bro[1] = E;
    }
    __syncthreads();
    m = bro[0]; e = bro[1];
    // safe to reuse sm/se immediately after: all reads of them complete before
    // the second barrier above.
}

// mean_zz[i][j] = sum_n mean_z[n,i]*mean_z[n,j] + N*var_z[i,j]
__global__ __launch_bounds__(256) void init_zz(const float* __restrict__ mean_z,
                                               const float* __restrict__ var_z,
                                               float* __restrict__ ws) {
    float* zz = ws + OFF_ZZ;
    int i = blockIdx.x / Z_DIM, j = blockIdx.x % Z_DIM;
    float s = 0.f;
    for (int n = threadIdx.x; n < N_DIM; n += 256)
        s += mean_z[n * Z_DIM + i] * mean_z[n * Z_DIM + j];
    #pragma unroll
    for (int off = 32; off > 0; off >>= 1) s += __shfl_xor(s, off);
    __shared__ float ls[4];
    if ((threadIdx.x & 63) == 0) ls[threadIdx.x >> 6] = s;
    __syncthreads();
    if (threadIdx.x == 0) {
        float t = ls[0] + ls[1] + ls[2] + ls[3];
        zz[blockIdx.x] = t + (float)N_DIM * var_z[blockIdx.x];
    }
}

// ZtR[z][p] += sum over this block's n-chunk of mean_z[n,z]*data[n,p]  (atomic)
// W0[z][p]  = sum_l mean_w[l,z,p]*alpha[l,z,p]                        (y==0 only)
__global__ __launch_bounds__(NT) void precompute_big(const float* __restrict__ data,
                                                     const float* __restrict__ mean_z,
                                                     const float* __restrict__ mw0,
                                                     const float* __restrict__ al0,
                                                     float* __restrict__ ws) {
    float* ZtR = ws + OFF_ZTR;
    float* W   = ws + OFF_W;
    __shared__ float mzs[NCHUNK * Z_DIM];   // 10 KB
    int n0 = blockIdx.y * NCHUNK;
    for (int i = threadIdx.x; i < NCHUNK * Z_DIM; i += NT)
        mzs[i] = mean_z[n0 * Z_DIM + i];
    __syncthreads();
    int p = blockIdx.x * NT + threadIdx.x;
    if (p >= P_DIM) return;

    float acc[Z_DIM];
    #pragma unroll
    for (int z = 0; z < Z_DIM; z++) acc[z] = 0.f;
    for (int r = 0; r < NCHUNK; r++) {
        float d = data[(size_t)(n0 + r) * P_DIM + p];
        #pragma unroll
        for (int z = 0; z < Z_DIM; z++) acc[z] += mzs[r * Z_DIM + z] * d;
    }
    #pragma unroll
    for (int z = 0; z < Z_DIM; z++) atomicAdd(&ZtR[(size_t)z * P_DIM + p], acc[z]);

    if (blockIdx.y == 0) {
        #pragma unroll
        for (int z = 0; z < Z_DIM; z++) {
            float w = 0.f;
            #pragma unroll
            for (int l = 0; l < L_DIM; l++) {
                size_t io = ((size_t)l * Z_DIM + z) * P_DIM + p;
                w += mw0[io] * al0[io];
            }
            W[(size_t)z * P_DIM + p] = w;
        }
    }
}

// One sequential step (k,l). Finalizes step (pk,pl) first (global softmax via
// stream-ordered partials), then computes this step's logits + partials.
__global__ __launch_bounds__(NT) void step_kernel(const float* __restrict__ mw0,
                                                  const float* __restrict__ al0,
                                                  const float* __restrict__ pi,
                                                  const float* __restrict__ tau0,
                                                  const float* __restrict__ taup,
                                                  float* __restrict__ ws,
                                                  float* __restrict__ out,
                                                  int k, int l, int pk, int pl,
                                                  int has_prev, int prev_last, int s) {
    float* ZtR = ws + OFF_ZTR;
    float* W   = ws + OFF_W;
    float* Wk  = ws + OFF_WK;
    float* RtZ = ws + OFF_RTZ;
    float* lg  = ws + OFF_LG;
    float* zz  = ws + OFF_ZZ;
    int wbuf = s & 1, rbuf = 1 - wbuf;
    float* pm_r = ws + (rbuf ? OFF_PM1 : OFF_PM0);
    float* ps_r = ws + (rbuf ? OFF_PS1 : OFF_PS0);
    float* pm_w = ws + (wbuf ? OFF_PM1 : OFF_PM0);
    float* ps_w = ws + (wbuf ? OFF_PS1 : OFF_PS0);

    float* out_mw = out + OUT_MW;
    float* out_vw = out + OUT_VW;
    float* out_al = out + OUT_AL;

    __shared__ float sm[NT / 64], se[NT / 64], bro[2];

    int tid = threadIdx.x;
    int p = blockIdx.x * NT + tid;
    bool valid = p < P_DIM;
    float tau = taup[0];

    float wk = 0.f;

    // ---- finalize previous step ----
    if (has_prev) {
        float m = NEG_BIG, e = 0.f;
        if (tid < NB) { m = pm_r[tid]; e = ps_r[tid]; }
        block_merge(m, e, sm, se, bro);
        float M = m, S = e;
        if (valid) {
            float a = __expf(lg[p] - M) / S;
            size_t po = ((size_t)pl * Z_DIM + pk) * P_DIM + p;
            out_al[po] = a;
            float um = out_mw[po];
            wk = Wk[p] + um * a;                 // Wk after effect (pk,pl)
            if (prev_last) W[(size_t)pk * P_DIM + p] = wk;
        }
    }

    // ---- per-step scalars ----
    float Ezz   = zz[k * Z_DIM + k];
    float t0v   = tau0[l * Z_DIM + k];
    float u_var = 1.f / (tau * Ezz + t0v);
    float s2    = 1.f / (Ezz * tau);
    float s0inv = 1.f / t0v;
    float cq    = 0.5f * (tau / Ezz) * (s0inv / (s2 + s0inv));

    float r = 0.f;
    if (valid) {
        if (l == 0) {
            r = ZtR[(size_t)k * P_DIM + p];
            #pragma unroll
            for (int j = 0; j < Z_DIM; j++) {
                if (j == k) continue;
                float wj = (has_prev && prev_last && j == pk) ? wk
                                                              : W[(size_t)j * P_DIM + p];
                r -= zz[k * Z_DIM + j] * wj;
            }
            RtZ[p] = r;
            wk = W[(size_t)k * P_DIM + p];       // fresh Wk for new k
        } else {
            r = RtZ[p];                           // wk carried from finalize
        }
    }

    // ---- compute step (k,l) ----
    float m = NEG_BIG, e = 0.f;
    if (valid) {
        size_t io = ((size_t)l * Z_DIM + k) * P_DIM + p;
        float wkl = wk - mw0[io] * al0[io];
        float E   = r - Ezz * wkl;
        float um  = tau * u_var * E;
        float lgt = __logf(pi[(size_t)k * P_DIM + p]) + cq * E * E;
        out_mw[io] = um;
        lg[p] = lgt;
        Wk[p] = wkl;
        m = lgt; e = 1.f;
    }
    block_merge(m, e, sm, se, bro);
    if (tid == 0) { pm_w[blockIdx.x] = m; ps_w[blockIdx.x] = e; }
    if (tid == 0 && blockIdx.x == 0) out_vw[l * Z_DIM + k] = u_var;
}

// Finalize the last step (k=9,l=4): just alpha.
__global__ __launch_bounds__(NT) void final_kernel(float* __restrict__ ws,
                                                   float* __restrict__ out, int s_last) {
    float* lg = ws + OFF_LG;
    int rbuf = s_last & 1;
    float* pm_r = ws + (rbuf ? OFF_PM1 : OFF_PM0);
    float* ps_r = ws + (rbuf ? OFF_PS1 : OFF_PS0);
    float* out_al = out + OUT_AL;

    __shared__ float sm[NT / 64], se[NT / 64], bro[2];
    int tid = threadIdx.x;
    int p = blockIdx.x * NT + tid;

    float m = NEG_BIG, e = 0.f;
    if (tid < NB) { m = pm_r[tid]; e = ps_r[tid]; }
    block_merge(m, e, sm, se, bro);
    if (p < P_DIM) {
        float a = __expf(lg[p] - m) / e;
        out_al[((size_t)4 * Z_DIM + 9) * P_DIM + p] = a;
    }
}

extern "C" void kernel_launch(void* const* d_in, const int* in_sizes, int n_in,
                              void* d_out, int out_size, void* d_ws, size_t ws_size,
                              hipStream_t stream) {
    (void)in_sizes; (void)n_in; (void)out_size; (void)ws_size;
    const float* data   = (const float*)d_in[0];
    const float* mean_z = (const float*)d_in[1];
    const float* var_z  = (const float*)d_in[2];
    const float* mw0    = (const float*)d_in[3];
    // d_in[4] var_w: unused (fully overwritten in output)
    const float* al0    = (const float*)d_in[5];
    const float* tau0   = (const float*)d_in[6];
    const float* pi     = (const float*)d_in[7];
    const float* taup   = (const float*)d_in[8];
    float* out = (float*)d_out;
    float* ws  = (float*)d_ws;

    // zero ZtR accumulator (ws is poisoned 0xAA before every call)
    hipMemsetAsync(ws, 0, ZP * sizeof(float), stream);
    init_zz<<<Z_DIM * Z_DIM, 256, 0, stream>>>(mean_z, var_z, ws);
    precompute_big<<<dim3(NB, NSPLIT), NT, 0, stream>>>(data, mean_z, mw0, al0, ws);

    for (int s = 0; s < Z_DIM * L_DIM; s++) {
        int k = s / L_DIM, l = s % L_DIM;
        int pk = (s > 0) ? (s - 1) / L_DIM : 0;
        int pl = (s > 0) ? (s - 1) % L_DIM : 0;
        int has_prev  = (s > 0) ? 1 : 0;
        int prev_last = (has_prev && pl == L_DIM - 1) ? 1 : 0;
        step_kernel<<<NB, NT, 0, stream>>>(mw0, al0, pi, tau0, taup, ws, out,
                                           k, l, pk, pl, has_prev, prev_last, s);
    }
    final_kernel<<<NB, NT, 0, stream>>>(ws, out, Z_DIM * L_DIM - 1);
}